// Round 7
// baseline (337.282 us; speedup 1.0000x reference)
//
#include <hip/hip_runtime.h>
#include <hip/hip_bf16.h>
#include <math.h>

#define N_NODES 50000
#define N_EDGES 800000
#define HEADS 4
#define HD 256           // HEADS*OUT
#define NEG_SLOPE 0.2f

typedef __attribute__((ext_vector_type(8))) short bf16x8;
typedef __attribute__((ext_vector_type(4))) float f32x4;

// ---------------- device scratch (module globals — proven fast in R4) ------
__device__ unsigned short g_Hb[N_NODES * HD];   // 25.6 MB projected nodes (bf16)
__device__ float    g_el[N_NODES * HEADS];
__device__ float    g_er[N_NODES * HEADS];
__device__ float    g_ebuf[N_EDGES * HEADS];    // 12.8 MB exp(edge logits), edge order
__device__ float    g_esort[N_EDGES * HEADS];   // 12.8 MB exp, dst-sorted order
__device__ int      g_srcs[N_EDGES];            // src, dst-sorted order
__device__ int      g_deg[N_NODES];
__device__ int      g_rowptr[N_NODES + 1];
__device__ int      g_cursor[N_NODES];
__device__ float    g_Wea[64 * HEADS];
__device__ unsigned short g_Wbt[256 * 256];     // W^T bf16, [n][k]
__device__ unsigned short g_Wlrb[16 * 256];     // [Wl|Wr|0] bf16, [c][k]

// f32 -> bf16 bits, round-to-nearest-even
__device__ __forceinline__ unsigned short f2bf(float f) {
    unsigned u = __float_as_uint(f);
    u += 0x7fffu + ((u >> 16) & 1u);
    return (unsigned short)(u >> 16);
}
__device__ __forceinline__ float bf_lo(unsigned u) {
    return __uint_as_float(u << 16);
}
__device__ __forceinline__ float bf_hi(unsigned u) {
    return __uint_as_float(u & 0xFFFF0000u);
}

// ---------------- prep: zero deg + fold attn tables + bf16 W^T -------------
// grid 196*256 = 50176 threads
__global__ void k_prep2(const float* __restrict__ W, const float* __restrict__ We,
                        const float* __restrict__ al, const float* __restrict__ ar,
                        const float* __restrict__ ae) {
    int t = blockIdx.x * 256 + threadIdx.x;
    if (t < N_NODES) g_deg[t] = 0;
    if (t < 256) {                               // Wea[k][h], t = k*4+h
        int k = t >> 2, h = t & 3;
        float s = 0.f;
        for (int d = 0; d < 64; ++d) s += We[k * 256 + h * 64 + d] * ae[h * 64 + d];
        g_Wea[t] = s;
    }
    if (t < 4096) {                              // Wlrb[c][k]: c<4 el, 4..7 er, rest 0
        int c = t >> 8, k = t & 255;
        float s = 0.f;
        if (c < 4) {
            for (int d = 0; d < 64; ++d) s += W[k * 256 + c * 64 + d] * al[c * 64 + d];
        } else if (c < 8) {
            int h = c - 4;
            for (int d = 0; d < 64; ++d) s += W[k * 256 + h * 64 + d] * ar[h * 64 + d];
        }
        g_Wlrb[c * 256 + k] = f2bf(s);
    }
    for (int i = t; i < 65536; i += 50176) {     // Wbt[n][k] = bf16(W[k][n])
        int n = i >> 8, k = i & 255;
        g_Wbt[n * 256 + k] = f2bf(W[k * 256 + n]);
    }
}

// ---------------- h = X @ W (bf16 MFMA) + fused el/er ----------------------
// A frag (16x16x32): lane l holds A[l&15][(l>>4)*8 + j], j=0..7
// B frag:            lane l holds B[(l>>4)*8 + j][l&15]
// D frag:            lane l reg r -> D[(l>>4)*4 + r][l&15]
#define BM 128
#define BK 32
__global__ __launch_bounds__(256) void k_gemm_mfma(const float* __restrict__ X) {
    __shared__ unsigned short As[BM][40];
    const int tid = threadIdx.x;
    const int wave = tid >> 6, lane = tid & 63;
    const int l15 = lane & 15, lg = lane >> 4;
    const int row0 = blockIdx.x * BM;

    f32x4 acc[8][4];
    f32x4 accE[8];
    #pragma unroll
    for (int i = 0; i < 8; ++i) {
        accE[i] = (f32x4){0.f, 0.f, 0.f, 0.f};
        #pragma unroll
        for (int j = 0; j < 4; ++j) acc[i][j] = (f32x4){0.f, 0.f, 0.f, 0.f};
    }

    for (int k0 = 0; k0 < 256; k0 += BK) {
        #pragma unroll
        for (int q = 0; q < 4; ++q) {
            int f = q * 256 + tid;
            int r = f >> 3;
            int kq = (f & 7) << 2;
            int grow = row0 + r;
            float4 v = make_float4(0.f, 0.f, 0.f, 0.f);
            if (grow < N_NODES) v = *(const float4*)(X + grow * 256 + k0 + kq);
            ushort4 b;
            b.x = f2bf(v.x); b.y = f2bf(v.y); b.z = f2bf(v.z); b.w = f2bf(v.w);
            *(ushort4*)&As[r][kq] = b;
        }
        bf16x8 bfr[4];
        #pragma unroll
        for (int nf = 0; nf < 4; ++nf) {
            int n = wave * 64 + nf * 16 + l15;
            bfr[nf] = *(const bf16x8*)(g_Wbt + n * 256 + k0 + lg * 8);
        }
        bf16x8 bfrE = *(const bf16x8*)(g_Wlrb + l15 * 256 + k0 + lg * 8);
        __syncthreads();
        #pragma unroll
        for (int mf = 0; mf < 8; ++mf) {
            bf16x8 afr = *(const bf16x8*)&As[mf * 16 + l15][lg * 8];
            #pragma unroll
            for (int nf = 0; nf < 4; ++nf)
                acc[mf][nf] = __builtin_amdgcn_mfma_f32_16x16x32_bf16(
                    afr, bfr[nf], acc[mf][nf], 0, 0, 0);
            accE[mf] = __builtin_amdgcn_mfma_f32_16x16x32_bf16(
                afr, bfrE, accE[mf], 0, 0, 0);
        }
        __syncthreads();
    }
    #pragma unroll
    for (int mf = 0; mf < 8; ++mf) {
        #pragma unroll
        for (int r = 0; r < 4; ++r) {
            int grow = row0 + mf * 16 + lg * 4 + r;
            if (grow < N_NODES) {
                #pragma unroll
                for (int nf = 0; nf < 4; ++nf) {
                    int col = wave * 64 + nf * 16 + l15;
                    g_Hb[grow * 256 + col] = f2bf(acc[mf][nf][r]);
                }
                if (wave == 0) {
                    if (l15 < 4) g_el[grow * 4 + l15] = accE[mf][r];
                    else if (l15 < 8) g_er[grow * 4 + (l15 - 4)] = accE[mf][r];
                }
            }
        }
    }
}

// ---------------- per-edge: ee dot + logits + exp + fused histogram --------
__global__ __launch_bounds__(256) void k_edge(const float* __restrict__ EF,
                                              const int* __restrict__ src,
                                              const int* __restrict__ dst) {
    __shared__ float sEF[32][258];
    __shared__ float4 sW[64];
    const int tid = threadIdx.x;
    if (tid < 64) sW[tid] = *(const float4*)(g_Wea + tid * 4);
    const int e0 = blockIdx.x * 256;

    float p0 = 0.f, p1 = 0.f, p2 = 0.f, p3 = 0.f;
    #pragma unroll
    for (int kc = 0; kc < 2; ++kc) {
        __syncthreads();
        #pragma unroll
        for (int q = 0; q < 8; ++q) {
            int f = q * 256 + tid;
            int e = f >> 3;
            int c = (f & 7) << 2;
            float4 v = *(const float4*)(EF + (size_t)(e0 + e) * 64 + kc * 32 + c);
            sEF[c + 0][e] = v.x; sEF[c + 1][e] = v.y;
            sEF[c + 2][e] = v.z; sEF[c + 3][e] = v.w;
        }
        __syncthreads();
        #pragma unroll
        for (int k = 0; k < 32; ++k) {
            float x = sEF[k][tid];
            float4 w = sW[kc * 32 + k];
            p0 += x * w.x; p1 += x * w.y; p2 += x * w.z; p3 += x * w.w;
        }
    }
    const int eid = e0 + tid;
    const int s = src[eid], d = dst[eid];
    float4 l4 = *(const float4*)(g_el + s * 4);
    float4 r4 = *(const float4*)(g_er + d * 4);
    float e0v = p0 + l4.x + r4.x;
    float e1v = p1 + l4.y + r4.y;
    float e2v = p2 + l4.z + r4.z;
    float e3v = p3 + l4.w + r4.w;
    e0v = e0v > 0.f ? e0v : NEG_SLOPE * e0v;
    e1v = e1v > 0.f ? e1v : NEG_SLOPE * e1v;
    e2v = e2v > 0.f ? e2v : NEG_SLOPE * e2v;
    e3v = e3v > 0.f ? e3v : NEG_SLOPE * e3v;
    // no segment-max shift needed: |e| <~ 12, exp() safely in f32 range
    *(float4*)(g_ebuf + eid * 4) =
        make_float4(__expf(e0v), __expf(e1v), __expf(e2v), __expf(e3v));
    atomicAdd(&g_deg[d], 1);
}

// ---------------- single-block exclusive scan -> rowptr + cursor -----------
#define SCHUNK 49   // 1024*49 = 50176 >= N_NODES
__global__ __launch_bounds__(1024) void k_scan() {
    __shared__ int ssum[1024];
    const int t = threadIdx.x;
    const int base = t * SCHUNK;
    int loc[SCHUNK];
    int s = 0;
    #pragma unroll
    for (int i = 0; i < SCHUNK; ++i) {
        int g = base + i;
        int v = (g < N_NODES) ? g_deg[g] : 0;
        loc[i] = s;
        s += v;
    }
    ssum[t] = s;
    __syncthreads();
    for (int o = 1; o < 1024; o <<= 1) {
        int v = (t >= o) ? ssum[t - o] : 0;
        __syncthreads();
        ssum[t] += v;
        __syncthreads();
    }
    int off = ssum[t] - s;                       // exclusive prefix of chunk
    #pragma unroll
    for (int i = 0; i < SCHUNK; ++i) {
        int g = base + i;
        if (g < N_NODES) {
            int r = off + loc[i];
            g_rowptr[g] = r;
            g_cursor[g] = r;
        }
    }
    if (t == 0) g_rowptr[N_NODES] = N_EDGES;
}

// ---------------- scatter edges into dst-sorted arrays (src + exp4) --------
__global__ void k_scatter(const int* __restrict__ src, const int* __restrict__ dst) {
    int e = blockIdx.x * 256 + threadIdx.x;
    if (e < N_EDGES) {
        int p = atomicAdd(&g_cursor[dst[e]], 1);
        g_srcs[p] = src[e];
        *(float4*)(g_esort + p * 4) = *(const float4*)(g_ebuf + e * 4);
    }
}

// ---------------- per-node fused softmax+aggregation (one wave/node) -------
__global__ __launch_bounds__(256) void k_agg(float* __restrict__ out) {
    int node = (blockIdx.x * 256 + threadIdx.x) >> 6;
    int lane = threadIdx.x & 63;
    if (node >= N_NODES) return;
    int start = g_rowptr[node], end = g_rowptr[node + 1];
    int myh = lane >> 4, sub = lane & 15;
    const int hoff = myh * 64 + sub * 4;

    float den = 0.f;
    float a0 = 0.f, a1 = 0.f, a2 = 0.f, a3 = 0.f;
    #pragma unroll 8
    for (int i = start; i < end; ++i) {
        float ex = g_esort[i * 4 + myh];          // broadcast within head group
        int s = g_srcs[i];                        // broadcast
        uint2 hv = *(const uint2*)(g_Hb + s * 256 + hoff);  // coalesced 512B/wave
        den += ex;
        a0 += ex * bf_lo(hv.x); a1 += ex * bf_hi(hv.x);
        a2 += ex * bf_lo(hv.y); a3 += ex * bf_hi(hv.y);
    }
    float rden = 1.0f / (den + 1e-9f);
    *(float4*)(out + node * 256 + lane * 4) =
        make_float4(a0 * rden, a1 * rden, a2 * rden, a3 * rden);
}

// ---------------- launch ----------------------------------------------------
extern "C" void kernel_launch(void* const* d_in, const int* in_sizes, int n_in,
                              void* d_out, int out_size, void* d_ws, size_t ws_size,
                              hipStream_t stream) {
    const float* X  = (const float*)d_in[0];
    const float* EF = (const float*)d_in[1];
    const float* W  = (const float*)d_in[2];
    const float* We = (const float*)d_in[3];
    const float* al = (const float*)d_in[4];
    const float* ar = (const float*)d_in[5];
    const float* ae = (const float*)d_in[6];
    const int* src  = (const int*)d_in[7];
    const int* dst  = (const int*)d_in[8];
    float* out = (float*)d_out;

    k_prep2<<<196, 256, 0, stream>>>(W, We, al, ar, ae);
    k_gemm_mfma<<<(N_NODES + BM - 1) / BM, 256, 0, stream>>>(X);
    k_edge<<<N_EDGES / 256, 256, 0, stream>>>(EF, src, dst);
    k_scan<<<1, 1024, 0, stream>>>();
    k_scatter<<<(N_EDGES + 255) / 256, 256, 0, stream>>>(src, dst);
    k_agg<<<(N_NODES + 3) / 4, 256, 0, stream>>>(out);
}

// Round 8
// 257.256 us; speedup vs baseline: 1.3111x; 1.3111x over previous
//
#include <hip/hip_runtime.h>
#include <hip/hip_bf16.h>
#include <math.h>

#define N_NODES 50000
#define N_EDGES 800000
#define HEADS 4
#define HD 256           // HEADS*OUT
#define NEG_SLOPE 0.2f

typedef __attribute__((ext_vector_type(8))) short bf16x8;
typedef __attribute__((ext_vector_type(4))) float f32x4;

// 32B packed per-edge payload in dst-sorted order: one cache segment per edge
struct __align__(32) EPack {
    float ex[4];   // exp(logit) per head
    int   s;       // src node
    int   pad[3];
};

// ---------------- device scratch (module globals — proven fast in R4) ------
__device__ unsigned short g_Hb[N_NODES * HD];   // 25.6 MB projected nodes (bf16)
__device__ float    g_el[N_NODES * HEADS];
__device__ float    g_er[N_NODES * HEADS];
__device__ EPack    g_ep[N_EDGES];              // 25.6 MB dst-sorted edge payload
__device__ int      g_deg[N_NODES];
__device__ int      g_rowptr[N_NODES + 1];
__device__ int      g_cursor[N_NODES];
__device__ int      g_bsum[256];
__device__ float    g_Wea[64 * HEADS];
__device__ unsigned short g_Wbt[256 * 256];     // W^T bf16, [n][k]
__device__ unsigned short g_Wlrb[16 * 256];     // [Wl|Wr|0] bf16, [c][k]

// f32 -> bf16 bits, round-to-nearest-even
__device__ __forceinline__ unsigned short f2bf(float f) {
    unsigned u = __float_as_uint(f);
    u += 0x7fffu + ((u >> 16) & 1u);
    return (unsigned short)(u >> 16);
}
__device__ __forceinline__ float bf_lo(unsigned u) {
    return __uint_as_float(u << 16);
}
__device__ __forceinline__ float bf_hi(unsigned u) {
    return __uint_as_float(u & 0xFFFF0000u);
}

// ---------------- zero deg --------------------------------------------------
__global__ void k_zero() {
    int g = blockIdx.x * 256 + threadIdx.x;
    if (g < N_NODES) g_deg[g] = 0;
}

// ---------------- prep: fold attn tables + bf16 W^T + dst histogram --------
// grid 196*256 = 50176 threads
__global__ void k_prep(const float* __restrict__ W, const float* __restrict__ We,
                       const float* __restrict__ al, const float* __restrict__ ar,
                       const float* __restrict__ ae, const int* __restrict__ dst) {
    int t = blockIdx.x * 256 + threadIdx.x;
    if (t < 256) {                               // Wea[k][h], t = k*4+h
        int k = t >> 2, h = t & 3;
        float s = 0.f;
        for (int d = 0; d < 64; ++d) s += We[k * 256 + h * 64 + d] * ae[h * 64 + d];
        g_Wea[t] = s;
    }
    if (t < 4096) {                              // Wlrb[c][k]: c<4 el, 4..7 er, rest 0
        int c = t >> 8, k = t & 255;
        float s = 0.f;
        if (c < 4) {
            for (int d = 0; d < 64; ++d) s += W[k * 256 + c * 64 + d] * al[c * 64 + d];
        } else if (c < 8) {
            int h = c - 4;
            for (int d = 0; d < 64; ++d) s += W[k * 256 + h * 64 + d] * ar[h * 64 + d];
        }
        g_Wlrb[c * 256 + k] = f2bf(s);
    }
    for (int i = t; i < 65536; i += 50176) {     // Wbt[n][k] = bf16(W[k][n])
        int n = i >> 8, k = i & 255;
        g_Wbt[n * 256 + k] = f2bf(W[k * 256 + n]);
    }
    for (int e = t; e < N_EDGES; e += 50176)     // dst-degree histogram
        atomicAdd(&g_deg[dst[e]], 1);
}

// ---------------- h = X @ W (bf16 MFMA) + fused el/er ----------------------
// A frag (16x16x32): lane l holds A[l&15][(l>>4)*8 + j], j=0..7
// B frag:            lane l holds B[(l>>4)*8 + j][l&15]
// D frag:            lane l reg r -> D[(l>>4)*4 + r][l&15]
#define BM 128
#define BK 32
__global__ __launch_bounds__(256) void k_gemm_mfma(const float* __restrict__ X) {
    __shared__ unsigned short As[BM][40];
    const int tid = threadIdx.x;
    const int wave = tid >> 6, lane = tid & 63;
    const int l15 = lane & 15, lg = lane >> 4;
    const int row0 = blockIdx.x * BM;

    f32x4 acc[8][4];
    f32x4 accE[8];
    #pragma unroll
    for (int i = 0; i < 8; ++i) {
        accE[i] = (f32x4){0.f, 0.f, 0.f, 0.f};
        #pragma unroll
        for (int j = 0; j < 4; ++j) acc[i][j] = (f32x4){0.f, 0.f, 0.f, 0.f};
    }

    for (int k0 = 0; k0 < 256; k0 += BK) {
        #pragma unroll
        for (int q = 0; q < 4; ++q) {
            int f = q * 256 + tid;
            int r = f >> 3;
            int kq = (f & 7) << 2;
            int grow = row0 + r;
            float4 v = make_float4(0.f, 0.f, 0.f, 0.f);
            if (grow < N_NODES) v = *(const float4*)(X + grow * 256 + k0 + kq);
            ushort4 b;
            b.x = f2bf(v.x); b.y = f2bf(v.y); b.z = f2bf(v.z); b.w = f2bf(v.w);
            *(ushort4*)&As[r][kq] = b;
        }
        bf16x8 bfr[4];
        #pragma unroll
        for (int nf = 0; nf < 4; ++nf) {
            int n = wave * 64 + nf * 16 + l15;
            bfr[nf] = *(const bf16x8*)(g_Wbt + n * 256 + k0 + lg * 8);
        }
        bf16x8 bfrE = *(const bf16x8*)(g_Wlrb + l15 * 256 + k0 + lg * 8);
        __syncthreads();
        #pragma unroll
        for (int mf = 0; mf < 8; ++mf) {
            bf16x8 afr = *(const bf16x8*)&As[mf * 16 + l15][lg * 8];
            #pragma unroll
            for (int nf = 0; nf < 4; ++nf)
                acc[mf][nf] = __builtin_amdgcn_mfma_f32_16x16x32_bf16(
                    afr, bfr[nf], acc[mf][nf], 0, 0, 0);
            accE[mf] = __builtin_amdgcn_mfma_f32_16x16x32_bf16(
                afr, bfrE, accE[mf], 0, 0, 0);
        }
        __syncthreads();
    }
    #pragma unroll
    for (int mf = 0; mf < 8; ++mf) {
        #pragma unroll
        for (int r = 0; r < 4; ++r) {
            int grow = row0 + mf * 16 + lg * 4 + r;
            if (grow < N_NODES) {
                #pragma unroll
                for (int nf = 0; nf < 4; ++nf) {
                    int col = wave * 64 + nf * 16 + l15;
                    g_Hb[grow * 256 + col] = f2bf(acc[mf][nf][r]);
                }
                if (wave == 0) {
                    if (l15 < 4) g_el[grow * 4 + l15] = accE[mf][r];
                    else if (l15 < 8) g_er[grow * 4 + (l15 - 4)] = accE[mf][r];
                }
            }
        }
    }
}

// ---------------- CSR scan (196-block, proven in R4) -----------------------
__global__ void k_scan1() {
    __shared__ int s[256];
    int tid = threadIdx.x;
    int g = blockIdx.x * 256 + tid;
    int v = (g < N_NODES) ? g_deg[g] : 0;
    s[tid] = v; __syncthreads();
    for (int o = 1; o < 256; o <<= 1) {
        int t = (tid >= o) ? s[tid - o] : 0;
        __syncthreads();
        s[tid] += t;
        __syncthreads();
    }
    if (g < N_NODES) g_rowptr[g] = s[tid] - v;
    if (tid == 255) g_bsum[blockIdx.x] = s[255];
}

__global__ void k_scan2(int nb) {
    __shared__ int s[256];
    int tid = threadIdx.x;
    int v = (tid < nb) ? g_bsum[tid] : 0;
    s[tid] = v; __syncthreads();
    for (int o = 1; o < 256; o <<= 1) {
        int t = (tid >= o) ? s[tid - o] : 0;
        __syncthreads();
        s[tid] += t;
        __syncthreads();
    }
    if (tid < nb) g_bsum[tid] = s[tid] - v;
}

__global__ void k_scan3() {
    int g = blockIdx.x * 256 + threadIdx.x;
    if (g < N_NODES) {
        int r = g_rowptr[g] + g_bsum[blockIdx.x];
        g_rowptr[g] = r;
        g_cursor[g] = r;
    }
    if (g == 0) g_rowptr[N_NODES] = N_EDGES;
}

// ---------------- per-edge: ee dot + logits + exp + direct sorted scatter --
__global__ __launch_bounds__(256) void k_edge(const float* __restrict__ EF,
                                              const int* __restrict__ src,
                                              const int* __restrict__ dst) {
    __shared__ float sEF[32][258];
    __shared__ float4 sW[64];
    const int tid = threadIdx.x;
    if (tid < 64) sW[tid] = *(const float4*)(g_Wea + tid * 4);
    const int e0 = blockIdx.x * 256;

    float p0 = 0.f, p1 = 0.f, p2 = 0.f, p3 = 0.f;
    #pragma unroll
    for (int kc = 0; kc < 2; ++kc) {
        __syncthreads();
        #pragma unroll
        for (int q = 0; q < 8; ++q) {
            int f = q * 256 + tid;
            int e = f >> 3;
            int c = (f & 7) << 2;
            float4 v = *(const float4*)(EF + (size_t)(e0 + e) * 64 + kc * 32 + c);
            sEF[c + 0][e] = v.x; sEF[c + 1][e] = v.y;
            sEF[c + 2][e] = v.z; sEF[c + 3][e] = v.w;
        }
        __syncthreads();
        #pragma unroll
        for (int k = 0; k < 32; ++k) {
            float x = sEF[k][tid];
            float4 w = sW[kc * 32 + k];
            p0 += x * w.x; p1 += x * w.y; p2 += x * w.z; p3 += x * w.w;
        }
    }
    const int eid = e0 + tid;
    const int s = src[eid], d = dst[eid];
    float4 l4 = *(const float4*)(g_el + s * 4);
    float4 r4 = *(const float4*)(g_er + d * 4);
    float e0v = p0 + l4.x + r4.x;
    float e1v = p1 + l4.y + r4.y;
    float e2v = p2 + l4.z + r4.z;
    float e3v = p3 + l4.w + r4.w;
    e0v = e0v > 0.f ? e0v : NEG_SLOPE * e0v;
    e1v = e1v > 0.f ? e1v : NEG_SLOPE * e1v;
    e2v = e2v > 0.f ? e2v : NEG_SLOPE * e2v;
    e3v = e3v > 0.f ? e3v : NEG_SLOPE * e3v;
    // no segment-max shift needed: |e| <~ 12, exp() safely in f32 range
    int p = atomicAdd(&g_cursor[d], 1);
    *(float4*)g_ep[p].ex =
        make_float4(__expf(e0v), __expf(e1v), __expf(e2v), __expf(e3v));
    g_ep[p].s = s;
}

// ---------------- per-node fused softmax+aggregation (one wave/node) -------
__global__ __launch_bounds__(256) void k_agg(float* __restrict__ out) {
    int node = (blockIdx.x * 256 + threadIdx.x) >> 6;
    int lane = threadIdx.x & 63;
    if (node >= N_NODES) return;
    int start = g_rowptr[node], end = g_rowptr[node + 1];
    int myh = lane >> 4, sub = lane & 15;
    const int hoff = myh * 64 + sub * 4;

    float den = 0.f;
    float a0 = 0.f, a1 = 0.f, a2 = 0.f, a3 = 0.f;
    #pragma unroll 8
    for (int i = start; i < end; ++i) {
        float ex = g_ep[i].ex[myh];               // one 32B segment per edge
        int s = g_ep[i].s;                        // same line, broadcast
        uint2 hv = *(const uint2*)(g_Hb + s * 256 + hoff);  // coalesced 512B/wave
        den += ex;
        a0 += ex * bf_lo(hv.x); a1 += ex * bf_hi(hv.x);
        a2 += ex * bf_lo(hv.y); a3 += ex * bf_hi(hv.y);
    }
    float rden = 1.0f / (den + 1e-9f);
    *(float4*)(out + node * 256 + lane * 4) =
        make_float4(a0 * rden, a1 * rden, a2 * rden, a3 * rden);
}

// ---------------- launch ----------------------------------------------------
extern "C" void kernel_launch(void* const* d_in, const int* in_sizes, int n_in,
                              void* d_out, int out_size, void* d_ws, size_t ws_size,
                              hipStream_t stream) {
    const float* X  = (const float*)d_in[0];
    const float* EF = (const float*)d_in[1];
    const float* W  = (const float*)d_in[2];
    const float* We = (const float*)d_in[3];
    const float* al = (const float*)d_in[4];
    const float* ar = (const float*)d_in[5];
    const float* ae = (const float*)d_in[6];
    const int* src  = (const int*)d_in[7];
    const int* dst  = (const int*)d_in[8];
    float* out = (float*)d_out;

    const int nb_scan = (N_NODES + 255) / 256;   // 196

    k_zero<<<nb_scan, 256, 0, stream>>>();
    k_prep<<<nb_scan, 256, 0, stream>>>(W, We, al, ar, ae, dst);
    k_gemm_mfma<<<(N_NODES + BM - 1) / BM, 256, 0, stream>>>(X);
    k_scan1<<<nb_scan, 256, 0, stream>>>();
    k_scan2<<<1, 256, 0, stream>>>(nb_scan);
    k_scan3<<<nb_scan, 256, 0, stream>>>();
    k_edge<<<N_EDGES / 256, 256, 0, stream>>>(EF, src, dst);
    k_agg<<<(N_NODES + 3) / 4, 256, 0, stream>>>(out);
}

// Round 9
// 247.144 us; speedup vs baseline: 1.3647x; 1.0409x over previous
//
#include <hip/hip_runtime.h>
#include <hip/hip_bf16.h>
#include <math.h>

#define N_NODES 50000
#define N_EDGES 800000
#define HEADS 4
#define HD 256           // HEADS*OUT
#define NEG_SLOPE 0.2f

typedef __attribute__((ext_vector_type(8))) short bf16x8;
typedef __attribute__((ext_vector_type(4))) float f32x4;

// 32B packed per-edge payload in dst-sorted order: one cache segment per edge
struct __align__(32) EPack {
    float ex[4];   // exp(logit) per head
    int   s;       // src node
    int   pad[3];
};

// ---------------- device scratch (module globals — proven fast in R4) ------
__device__ unsigned short g_Hb[N_NODES * HD];   // 25.6 MB projected nodes (bf16)
__device__ float    g_el[N_NODES * HEADS];
__device__ float    g_er[N_NODES * HEADS];
__device__ EPack    g_ep[N_EDGES];              // 25.6 MB dst-sorted edge payload
__device__ int      g_deg[N_NODES];
__device__ int      g_rowptr[N_NODES + 1];
__device__ int      g_cursor[N_NODES];
__device__ int      g_bsum[256];
__device__ float    g_Wea[64 * HEADS];
__device__ unsigned short g_Wbt[256 * 256];     // W^T bf16, [n][k]
__device__ unsigned short g_Wlrb[16 * 256];     // [Wl|Wr|0] bf16, [c][k]

// f32 -> bf16 bits, round-to-nearest-even
__device__ __forceinline__ unsigned short f2bf(float f) {
    unsigned u = __float_as_uint(f);
    u += 0x7fffu + ((u >> 16) & 1u);
    return (unsigned short)(u >> 16);
}
__device__ __forceinline__ float bf_lo(unsigned u) {
    return __uint_as_float(u << 16);
}
__device__ __forceinline__ float bf_hi(unsigned u) {
    return __uint_as_float(u & 0xFFFF0000u);
}

// ---------------- zero deg --------------------------------------------------
__global__ void k_zero() {
    int g = blockIdx.x * 256 + threadIdx.x;
    if (g < N_NODES) g_deg[g] = 0;
}

// ---------------- prep: fold attn tables + bf16 W^T + dst histogram --------
// grid 196*256 = 50176 threads
__global__ void k_prep(const float* __restrict__ W, const float* __restrict__ We,
                       const float* __restrict__ al, const float* __restrict__ ar,
                       const float* __restrict__ ae, const int* __restrict__ dst) {
    int t = blockIdx.x * 256 + threadIdx.x;
    if (t < 256) {                               // Wea[k][h], t = k*4+h
        int k = t >> 2, h = t & 3;
        float s = 0.f;
        for (int d = 0; d < 64; ++d) s += We[k * 256 + h * 64 + d] * ae[h * 64 + d];
        g_Wea[t] = s;
    }
    if (t < 4096) {                              // Wlrb[c][k]: c<4 el, 4..7 er, rest 0
        int c = t >> 8, k = t & 255;
        float s = 0.f;
        if (c < 4) {
            for (int d = 0; d < 64; ++d) s += W[k * 256 + c * 64 + d] * al[c * 64 + d];
        } else if (c < 8) {
            int h = c - 4;
            for (int d = 0; d < 64; ++d) s += W[k * 256 + h * 64 + d] * ar[h * 64 + d];
        }
        g_Wlrb[c * 256 + k] = f2bf(s);
    }
    for (int i = t; i < 65536; i += 50176) {     // Wbt[n][k] = bf16(W[k][n])
        int n = i >> 8, k = i & 255;
        g_Wbt[n * 256 + k] = f2bf(W[k * 256 + n]);
    }
    for (int e = t; e < N_EDGES; e += 50176)     // dst-degree histogram
        atomicAdd(&g_deg[dst[e]], 1);
}

// ---------------- h = X @ W (bf16 MFMA) + fused el/er ----------------------
// grid (391, 2): y = 128-col slab. BK=64, 2 N-frags/wave, ~150 VGPR.
// A frag (16x16x32): lane l holds A[l&15][(l>>4)*8 + j], j=0..7
// B frag:            lane l holds B[(l>>4)*8 + j][l&15]
// D frag:            lane l reg r -> D[(l>>4)*4 + r][l&15]
#define BM 128
#define BK 64
__global__ __launch_bounds__(256) void k_gemm_mfma(const float* __restrict__ X) {
    __shared__ unsigned short As[BM][BK + 8];
    const int tid = threadIdx.x;
    const int wave = tid >> 6, lane = tid & 63;
    const int l15 = lane & 15, lg = lane >> 4;
    const int row0 = blockIdx.x * BM;
    const int slab = blockIdx.y;                 // 0 or 1: cols slab*128..+127

    f32x4 acc[8][2];
    f32x4 accE[8];
    #pragma unroll
    for (int i = 0; i < 8; ++i) {
        accE[i] = (f32x4){0.f, 0.f, 0.f, 0.f};
        #pragma unroll
        for (int j = 0; j < 2; ++j) acc[i][j] = (f32x4){0.f, 0.f, 0.f, 0.f};
    }

    for (int k0 = 0; k0 < 256; k0 += BK) {
        // stage A: 128 rows x 64 k, f32 -> bf16 LDS (8 float4 per thread)
        #pragma unroll
        for (int q = 0; q < 8; ++q) {
            int f = q * 256 + tid;               // float4 id 0..2047
            int r = f >> 4;                      // 16 float4 per row
            int kq = (f & 15) << 2;
            int grow = row0 + r;
            float4 v = make_float4(0.f, 0.f, 0.f, 0.f);
            if (grow < N_NODES) v = *(const float4*)(X + grow * 256 + k0 + kq);
            ushort4 b;
            b.x = f2bf(v.x); b.y = f2bf(v.y); b.z = f2bf(v.z); b.w = f2bf(v.w);
            *(ushort4*)&As[r][kq] = b;
        }
        // B frags from L2 (pre-converted bf16, k-major): 2 k-chunks x 2 n-frags
        bf16x8 bfr[2][2], bfrE[2];
        #pragma unroll
        for (int kk = 0; kk < 2; ++kk) {
            #pragma unroll
            for (int nf = 0; nf < 2; ++nf) {
                int n = slab * 128 + wave * 32 + nf * 16 + l15;
                bfr[kk][nf] = *(const bf16x8*)(g_Wbt + n * 256 + k0 + kk * 32 + lg * 8);
            }
            bfrE[kk] = *(const bf16x8*)(g_Wlrb + l15 * 256 + k0 + kk * 32 + lg * 8);
        }
        __syncthreads();
        #pragma unroll
        for (int kk = 0; kk < 2; ++kk) {
            #pragma unroll
            for (int mf = 0; mf < 8; ++mf) {
                bf16x8 afr = *(const bf16x8*)&As[mf * 16 + l15][kk * 32 + lg * 8];
                #pragma unroll
                for (int nf = 0; nf < 2; ++nf)
                    acc[mf][nf] = __builtin_amdgcn_mfma_f32_16x16x32_bf16(
                        afr, bfr[kk][nf], acc[mf][nf], 0, 0, 0);
                if (slab == 0)
                    accE[mf] = __builtin_amdgcn_mfma_f32_16x16x32_bf16(
                        afr, bfrE[kk], accE[mf], 0, 0, 0);
            }
        }
        __syncthreads();
    }
    #pragma unroll
    for (int mf = 0; mf < 8; ++mf) {
        #pragma unroll
        for (int r = 0; r < 4; ++r) {
            int grow = row0 + mf * 16 + lg * 4 + r;
            if (grow < N_NODES) {
                #pragma unroll
                for (int nf = 0; nf < 2; ++nf) {
                    int col = slab * 128 + wave * 32 + nf * 16 + l15;
                    g_Hb[grow * 256 + col] = f2bf(acc[mf][nf][r]);
                }
                if (slab == 0 && wave == 0) {
                    if (l15 < 4) g_el[grow * 4 + l15] = accE[mf][r];
                    else if (l15 < 8) g_er[grow * 4 + (l15 - 4)] = accE[mf][r];
                }
            }
        }
    }
}

// ---------------- CSR scan (196-block, proven in R4) -----------------------
__global__ void k_scan1() {
    __shared__ int s[256];
    int tid = threadIdx.x;
    int g = blockIdx.x * 256 + tid;
    int v = (g < N_NODES) ? g_deg[g] : 0;
    s[tid] = v; __syncthreads();
    for (int o = 1; o < 256; o <<= 1) {
        int t = (tid >= o) ? s[tid - o] : 0;
        __syncthreads();
        s[tid] += t;
        __syncthreads();
    }
    if (g < N_NODES) g_rowptr[g] = s[tid] - v;
    if (tid == 255) g_bsum[blockIdx.x] = s[255];
}

__global__ void k_scan2(int nb) {
    __shared__ int s[256];
    int tid = threadIdx.x;
    int v = (tid < nb) ? g_bsum[tid] : 0;
    s[tid] = v; __syncthreads();
    for (int o = 1; o < 256; o <<= 1) {
        int t = (tid >= o) ? s[tid - o] : 0;
        __syncthreads();
        s[tid] += t;
        __syncthreads();
    }
    if (tid < nb) g_bsum[tid] = s[tid] - v;
}

__global__ void k_scan3() {
    int g = blockIdx.x * 256 + threadIdx.x;
    if (g < N_NODES) {
        int r = g_rowptr[g] + g_bsum[blockIdx.x];
        g_rowptr[g] = r;
        g_cursor[g] = r;
    }
    if (g == 0) g_rowptr[N_NODES] = N_EDGES;
}

// ---------------- per-edge: ee dot + logits + exp + direct sorted scatter --
__global__ __launch_bounds__(256) void k_edge(const float* __restrict__ EF,
                                              const int* __restrict__ src,
                                              const int* __restrict__ dst) {
    __shared__ float sEF[32][258];
    __shared__ float4 sW[64];
    const int tid = threadIdx.x;
    if (tid < 64) sW[tid] = *(const float4*)(g_Wea + tid * 4);
    const int e0 = blockIdx.x * 256;

    float p0 = 0.f, p1 = 0.f, p2 = 0.f, p3 = 0.f;
    #pragma unroll
    for (int kc = 0; kc < 2; ++kc) {
        __syncthreads();
        #pragma unroll
        for (int q = 0; q < 8; ++q) {
            int f = q * 256 + tid;
            int e = f >> 3;
            int c = (f & 7) << 2;
            float4 v = *(const float4*)(EF + (size_t)(e0 + e) * 64 + kc * 32 + c);
            sEF[c + 0][e] = v.x; sEF[c + 1][e] = v.y;
            sEF[c + 2][e] = v.z; sEF[c + 3][e] = v.w;
        }
        __syncthreads();
        #pragma unroll
        for (int k = 0; k < 32; ++k) {
            float x = sEF[k][tid];
            float4 w = sW[kc * 32 + k];
            p0 += x * w.x; p1 += x * w.y; p2 += x * w.z; p3 += x * w.w;
        }
    }
    const int eid = e0 + tid;
    const int s = src[eid], d = dst[eid];
    float4 l4 = *(const float4*)(g_el + s * 4);
    float4 r4 = *(const float4*)(g_er + d * 4);
    float e0v = p0 + l4.x + r4.x;
    float e1v = p1 + l4.y + r4.y;
    float e2v = p2 + l4.z + r4.z;
    float e3v = p3 + l4.w + r4.w;
    e0v = e0v > 0.f ? e0v : NEG_SLOPE * e0v;
    e1v = e1v > 0.f ? e1v : NEG_SLOPE * e1v;
    e2v = e2v > 0.f ? e2v : NEG_SLOPE * e2v;
    e3v = e3v > 0.f ? e3v : NEG_SLOPE * e3v;
    // no segment-max shift needed: |e| <~ 12, exp() safely in f32 range
    int p = atomicAdd(&g_cursor[d], 1);
    *(float4*)g_ep[p].ex =
        make_float4(__expf(e0v), __expf(e1v), __expf(e2v), __expf(e3v));
    g_ep[p].s = s;
}

// ---------------- per-node fused softmax+aggregation (one wave/node) -------
__global__ __launch_bounds__(256) void k_agg(float* __restrict__ out) {
    int node = (blockIdx.x * 256 + threadIdx.x) >> 6;
    int lane = threadIdx.x & 63;
    if (node >= N_NODES) return;
    int start = g_rowptr[node], end = g_rowptr[node + 1];
    int myh = lane >> 4, sub = lane & 15;
    const int hoff = myh * 64 + sub * 4;

    float den = 0.f;
    float a0 = 0.f, a1 = 0.f, a2 = 0.f, a3 = 0.f;
    #pragma unroll 8
    for (int i = start; i < end; ++i) {
        float ex = g_ep[i].ex[myh];               // one 32B segment per edge
        int s = g_ep[i].s;                        // same line, broadcast
        uint2 hv = *(const uint2*)(g_Hb + s * 256 + hoff);  // coalesced 512B/wave
        den += ex;
        a0 += ex * bf_lo(hv.x); a1 += ex * bf_hi(hv.x);
        a2 += ex * bf_lo(hv.y); a3 += ex * bf_hi(hv.y);
    }
    float rden = 1.0f / (den + 1e-9f);
    *(float4*)(out + node * 256 + lane * 4) =
        make_float4(a0 * rden, a1 * rden, a2 * rden, a3 * rden);
}

// ---------------- launch ----------------------------------------------------
extern "C" void kernel_launch(void* const* d_in, const int* in_sizes, int n_in,
                              void* d_out, int out_size, void* d_ws, size_t ws_size,
                              hipStream_t stream) {
    const float* X  = (const float*)d_in[0];
    const float* EF = (const float*)d_in[1];
    const float* W  = (const float*)d_in[2];
    const float* We = (const float*)d_in[3];
    const float* al = (const float*)d_in[4];
    const float* ar = (const float*)d_in[5];
    const float* ae = (const float*)d_in[6];
    const int* src  = (const int*)d_in[7];
    const int* dst  = (const int*)d_in[8];
    float* out = (float*)d_out;

    const int nb_scan = (N_NODES + 255) / 256;   // 196

    k_zero<<<nb_scan, 256, 0, stream>>>();
    k_prep<<<nb_scan, 256, 0, stream>>>(W, We, al, ar, ae, dst);
    k_gemm_mfma<<<dim3((N_NODES + BM - 1) / BM, 2), 256, 0, stream>>>(X);
    k_scan1<<<nb_scan, 256, 0, stream>>>();
    k_scan2<<<1, 256, 0, stream>>>(nb_scan);
    k_scan3<<<nb_scan, 256, 0, stream>>>();
    k_edge<<<N_EDGES / 256, 256, 0, stream>>>(EF, src, dst);
    k_agg<<<(N_NODES + 3) / 4, 256, 0, stream>>>(out);
}

// Round 11
// 243.709 us; speedup vs baseline: 1.3840x; 1.0141x over previous
//
#include <hip/hip_runtime.h>
#include <hip/hip_bf16.h>
#include <math.h>

#define N_NODES 50000
#define N_EDGES 800000
#define HEADS 4
#define HD 256           // HEADS*OUT
#define NEG_SLOPE 0.2f

typedef __attribute__((ext_vector_type(8))) short bf16x8;
typedef __attribute__((ext_vector_type(4))) float f32x4;
typedef __attribute__((ext_vector_type(4))) unsigned int u32x4;

// 32B packed per-edge payload in dst-sorted order: one cache segment per edge
struct __align__(32) EPack {
    float ex[4];   // exp(logit) per head
    int   s;       // src node
    int   pad[3];
};

// ---------------- device scratch (module globals — proven fast in R4) ------
__device__ unsigned short g_Hb[N_NODES * HD];   // 25.6 MB projected nodes (bf16)
__device__ float    g_el[N_NODES * HEADS];
__device__ float    g_er[N_NODES * HEADS];
__device__ EPack    g_ep[N_EDGES];              // 25.6 MB dst-sorted edge payload
__device__ int      g_deg[N_NODES];
__device__ int      g_rowptr[N_NODES + 1];
__device__ int      g_cursor[N_NODES];
__device__ int      g_bsum[256];
__device__ float    g_Wea[64 * HEADS];
__device__ unsigned short g_Wbt[256 * 256];     // W^T bf16, [n][k]
__device__ unsigned short g_Wlrb[16 * 256];     // [Wl|Wr|0] bf16, [c][k]

// f32 -> bf16 bits, round-to-nearest-even
__device__ __forceinline__ unsigned short f2bf(float f) {
    unsigned u = __float_as_uint(f);
    u += 0x7fffu + ((u >> 16) & 1u);
    return (unsigned short)(u >> 16);
}
__device__ __forceinline__ float bf_lo(unsigned u) {
    return __uint_as_float(u << 16);
}
__device__ __forceinline__ float bf_hi(unsigned u) {
    return __uint_as_float(u & 0xFFFF0000u);
}

// ---------------- zero deg --------------------------------------------------
__global__ void k_zero() {
    int g = blockIdx.x * 256 + threadIdx.x;
    if (g < N_NODES) g_deg[g] = 0;
}

// ---------------- prep: fold attn tables + bf16 W^T + dst histogram --------
// grid 196*256 = 50176 threads
__global__ void k_prep(const float* __restrict__ W, const float* __restrict__ We,
                       const float* __restrict__ al, const float* __restrict__ ar,
                       const float* __restrict__ ae, const int* __restrict__ dst) {
    int t = blockIdx.x * 256 + threadIdx.x;
    if (t < 256) {                               // Wea[k][h], t = k*4+h
        int k = t >> 2, h = t & 3;
        float s = 0.f;
        for (int d = 0; d < 64; ++d) s += We[k * 256 + h * 64 + d] * ae[h * 64 + d];
        g_Wea[t] = s;
    }
    if (t < 4096) {                              // Wlrb[c][k]: c<4 el, 4..7 er, rest 0
        int c = t >> 8, k = t & 255;
        float s = 0.f;
        if (c < 4) {
            for (int d = 0; d < 64; ++d) s += W[k * 256 + c * 64 + d] * al[c * 64 + d];
        } else if (c < 8) {
            int h = c - 4;
            for (int d = 0; d < 64; ++d) s += W[k * 256 + h * 64 + d] * ar[h * 64 + d];
        }
        g_Wlrb[c * 256 + k] = f2bf(s);
    }
    for (int i = t; i < 65536; i += 50176) {     // Wbt[n][k] = bf16(W[k][n])
        int n = i >> 8, k = i & 255;
        g_Wbt[n * 256 + k] = f2bf(W[k * 256 + n]);
    }
    for (int e = t; e < N_EDGES; e += 50176)     // dst-degree histogram
        atomicAdd(&g_deg[dst[e]], 1);
}

// ---------------- h = X @ W (bf16 MFMA) + fused el/er ----------------------
// grid (391, 2): y = 128-col slab. BK=64, 2 N-frags/wave, ~150 VGPR.
#define BM 128
#define BK 64
__global__ __launch_bounds__(256) void k_gemm_mfma(const float* __restrict__ X) {
    __shared__ unsigned short As[BM][BK + 8];
    const int tid = threadIdx.x;
    const int wave = tid >> 6, lane = tid & 63;
    const int l15 = lane & 15, lg = lane >> 4;
    const int row0 = blockIdx.x * BM;
    const int slab = blockIdx.y;                 // 0 or 1: cols slab*128..+127

    f32x4 acc[8][2];
    f32x4 accE[8];
    #pragma unroll
    for (int i = 0; i < 8; ++i) {
        accE[i] = (f32x4){0.f, 0.f, 0.f, 0.f};
        #pragma unroll
        for (int j = 0; j < 2; ++j) acc[i][j] = (f32x4){0.f, 0.f, 0.f, 0.f};
    }

    for (int k0 = 0; k0 < 256; k0 += BK) {
        #pragma unroll
        for (int q = 0; q < 8; ++q) {
            int f = q * 256 + tid;               // float4 id 0..2047
            int r = f >> 4;                      // 16 float4 per row
            int kq = (f & 15) << 2;
            int grow = row0 + r;
            float4 v = make_float4(0.f, 0.f, 0.f, 0.f);
            if (grow < N_NODES) v = *(const float4*)(X + grow * 256 + k0 + kq);
            ushort4 b;
            b.x = f2bf(v.x); b.y = f2bf(v.y); b.z = f2bf(v.z); b.w = f2bf(v.w);
            *(ushort4*)&As[r][kq] = b;
        }
        bf16x8 bfr[2][2], bfrE[2];
        #pragma unroll
        for (int kk = 0; kk < 2; ++kk) {
            #pragma unroll
            for (int nf = 0; nf < 2; ++nf) {
                int n = slab * 128 + wave * 32 + nf * 16 + l15;
                bfr[kk][nf] = *(const bf16x8*)(g_Wbt + n * 256 + k0 + kk * 32 + lg * 8);
            }
            bfrE[kk] = *(const bf16x8*)(g_Wlrb + l15 * 256 + k0 + kk * 32 + lg * 8);
        }
        __syncthreads();
        #pragma unroll
        for (int kk = 0; kk < 2; ++kk) {
            #pragma unroll
            for (int mf = 0; mf < 8; ++mf) {
                bf16x8 afr = *(const bf16x8*)&As[mf * 16 + l15][kk * 32 + lg * 8];
                #pragma unroll
                for (int nf = 0; nf < 2; ++nf)
                    acc[mf][nf] = __builtin_amdgcn_mfma_f32_16x16x32_bf16(
                        afr, bfr[kk][nf], acc[mf][nf], 0, 0, 0);
                if (slab == 0)
                    accE[mf] = __builtin_amdgcn_mfma_f32_16x16x32_bf16(
                        afr, bfrE[kk], accE[mf], 0, 0, 0);
            }
        }
        __syncthreads();
    }
    #pragma unroll
    for (int mf = 0; mf < 8; ++mf) {
        #pragma unroll
        for (int r = 0; r < 4; ++r) {
            int grow = row0 + mf * 16 + lg * 4 + r;
            if (grow < N_NODES) {
                #pragma unroll
                for (int nf = 0; nf < 2; ++nf) {
                    int col = slab * 128 + wave * 32 + nf * 16 + l15;
                    g_Hb[grow * 256 + col] = f2bf(acc[mf][nf][r]);
                }
                if (slab == 0 && wave == 0) {
                    if (l15 < 4) g_el[grow * 4 + l15] = accE[mf][r];
                    else if (l15 < 8) g_er[grow * 4 + (l15 - 4)] = accE[mf][r];
                }
            }
        }
    }
}

// ---------------- CSR scan (196-block; scan2 folded into scan3) ------------
__global__ void k_scan1() {
    __shared__ int s[256];
    int tid = threadIdx.x;
    int g = blockIdx.x * 256 + tid;
    int v = (g < N_NODES) ? g_deg[g] : 0;
    s[tid] = v; __syncthreads();
    for (int o = 1; o < 256; o <<= 1) {
        int t = (tid >= o) ? s[tid - o] : 0;
        __syncthreads();
        s[tid] += t;
        __syncthreads();
    }
    if (g < N_NODES) g_rowptr[g] = s[tid] - v;
    if (tid == 255) g_bsum[blockIdx.x] = s[255];
}

// each block redundantly scans the 196 block sums, then applies its offset
__global__ void k_scan3(int nb) {
    __shared__ int sb[256];
    int tid = threadIdx.x;
    int v = (tid < nb) ? g_bsum[tid] : 0;
    sb[tid] = v; __syncthreads();
    for (int o = 1; o < 256; o <<= 1) {
        int t = (tid >= o) ? sb[tid - o] : 0;
        __syncthreads();
        sb[tid] += t;
        __syncthreads();
    }
    int boff = sb[blockIdx.x] - g_bsum[blockIdx.x];  // exclusive prefix
    int g = blockIdx.x * 256 + tid;
    if (g < N_NODES) {
        int r = g_rowptr[g] + boff;
        g_rowptr[g] = r;
        g_cursor[g] = r;
    }
    if (g == 0) g_rowptr[N_NODES] = N_EDGES;
}

// ---------------- per-edge: ee dot + logits + exp + direct sorted scatter --
__global__ __launch_bounds__(256) void k_edge(const float* __restrict__ EF,
                                              const int* __restrict__ src,
                                              const int* __restrict__ dst) {
    __shared__ float sEF[32][258];
    __shared__ float4 sW[64];
    const int tid = threadIdx.x;
    if (tid < 64) sW[tid] = *(const float4*)(g_Wea + tid * 4);
    const int e0 = blockIdx.x * 256;

    float p0 = 0.f, p1 = 0.f, p2 = 0.f, p3 = 0.f;
    #pragma unroll
    for (int kc = 0; kc < 2; ++kc) {
        __syncthreads();
        #pragma unroll
        for (int q = 0; q < 8; ++q) {
            int f = q * 256 + tid;
            int e = f >> 3;
            int c = (f & 7) << 2;
            // single-use 205 MB stream: don't pollute L2 (el/er tables live there)
            f32x4 v = __builtin_nontemporal_load(
                (const f32x4*)(EF + (size_t)(e0 + e) * 64 + kc * 32 + c));
            sEF[c + 0][e] = v.x; sEF[c + 1][e] = v.y;
            sEF[c + 2][e] = v.z; sEF[c + 3][e] = v.w;
        }
        __syncthreads();
        #pragma unroll
        for (int k = 0; k < 32; ++k) {
            float x = sEF[k][tid];
            float4 w = sW[kc * 32 + k];
            p0 += x * w.x; p1 += x * w.y; p2 += x * w.z; p3 += x * w.w;
        }
    }
    const int eid = e0 + tid;
    const int s = src[eid], d = dst[eid];
    float4 l4 = *(const float4*)(g_el + s * 4);
    float4 r4 = *(const float4*)(g_er + d * 4);
    float e0v = p0 + l4.x + r4.x;
    float e1v = p1 + l4.y + r4.y;
    float e2v = p2 + l4.z + r4.z;
    float e3v = p3 + l4.w + r4.w;
    e0v = e0v > 0.f ? e0v : NEG_SLOPE * e0v;
    e1v = e1v > 0.f ? e1v : NEG_SLOPE * e1v;
    e2v = e2v > 0.f ? e2v : NEG_SLOPE * e2v;
    e3v = e3v > 0.f ? e3v : NEG_SLOPE * e3v;
    // no segment-max shift needed: |e| <~ 12, exp() safely in f32 range
    int p = atomicAdd(&g_cursor[d], 1);
    *(float4*)g_ep[p].ex =
        make_float4(__expf(e0v), __expf(e1v), __expf(e2v), __expf(e3v));
    g_ep[p].s = s;   // scattered writes stay cached (L2 line-coalescing)
}

// ---------------- per-node fused softmax+aggregation (one wave/node) -------
// two edges in flight per wave: lanes 0-31 edge i, lanes 32-63 edge i+1;
// each lane gathers 16B (8 dims) of the src row.
__global__ __launch_bounds__(256) void k_agg(float* __restrict__ out) {
    int node = (blockIdx.x * 256 + threadIdx.x) >> 6;
    int lane = threadIdx.x & 63;
    if (node >= N_NODES) return;
    int start = g_rowptr[node], end = g_rowptr[node + 1];
    const int half = lane >> 5;
    const int hl = lane & 31;
    const int myh = hl >> 3, sub = lane & 7;
    const int hoff = myh * 64 + sub * 8;          // bf16 element offset

    float den = 0.f;
    float a[8] = {};
    #pragma unroll 4
    for (int i = start + half; i < end; i += 2) {
        float ex = __builtin_nontemporal_load(&g_ep[i].ex[myh]);  // single-use stream
        int s    = __builtin_nontemporal_load(&g_ep[i].s);
        u32x4 hv = *(const u32x4*)(g_Hb + s * 256 + hoff);        // cached gather
        den += ex;
        a[0] += ex * bf_lo(hv.x); a[1] += ex * bf_hi(hv.x);
        a[2] += ex * bf_lo(hv.y); a[3] += ex * bf_hi(hv.y);
        a[4] += ex * bf_lo(hv.z); a[5] += ex * bf_hi(hv.z);
        a[6] += ex * bf_lo(hv.w); a[7] += ex * bf_hi(hv.w);
    }
    // merge the two halves
    den += __shfl_xor(den, 32);
    #pragma unroll
    for (int k = 0; k < 8; ++k) a[k] += __shfl_xor(a[k], 32);
    float rden = 1.0f / (den + 1e-9f);
    f32x4 o = half ? (f32x4){a[4] * rden, a[5] * rden, a[6] * rden, a[7] * rden}
                   : (f32x4){a[0] * rden, a[1] * rden, a[2] * rden, a[3] * rden};
    __builtin_nontemporal_store(o, (f32x4*)(out + node * 256 + hoff + half * 4));
}

// ---------------- launch ----------------------------------------------------
extern "C" void kernel_launch(void* const* d_in, const int* in_sizes, int n_in,
                              void* d_out, int out_size, void* d_ws, size_t ws_size,
                              hipStream_t stream) {
    const float* X  = (const float*)d_in[0];
    const float* EF = (const float*)d_in[1];
    const float* W  = (const float*)d_in[2];
    const float* We = (const float*)d_in[3];
    const float* al = (const float*)d_in[4];
    const float* ar = (const float*)d_in[5];
    const float* ae = (const float*)d_in[6];
    const int* src  = (const int*)d_in[7];
    const int* dst  = (const int*)d_in[8];
    float* out = (float*)d_out;

    const int nb_scan = (N_NODES + 255) / 256;   // 196

    k_zero<<<nb_scan, 256, 0, stream>>>();
    k_prep<<<nb_scan, 256, 0, stream>>>(W, We, al, ar, ae, dst);
    k_gemm_mfma<<<dim3((N_NODES + BM - 1) / BM, 2), 256, 0, stream>>>(X);
    k_scan1<<<nb_scan, 256, 0, stream>>>();
    k_scan3<<<nb_scan, 256, 0, stream>>>(nb_scan);
    k_edge<<<N_EDGES / 256, 256, 0, stream>>>(EF, src, dst);
    k_agg<<<(N_NODES + 3) / 4, 256, 0, stream>>>(out);
}